// Round 14
// baseline (6594.787 us; speedup 1.0000x reference)
//
#include <hip/hip_runtime.h>
#include <hip/hip_bf16.h>
#include <hip/hip_fp16.h>
#include <stdint.h>

#define BB 64
#define TT 512
#define II 256
#define HH 1024
#define G4 4096
#define SENT 0x7C00u            // fp16 +inf: |h| < 1 so live data NEVER equals this

typedef unsigned short u16;
typedef unsigned long long u64;
typedef __attribute__((ext_vector_type(8))) _Float16 h8;
typedef __attribute__((ext_vector_type(4))) float f32x4;

__device__ __forceinline__ u16 f2h(float x){
  _Float16 h = (_Float16)x;
  return __builtin_bit_cast(u16, h);
}
__device__ __forceinline__ float sigm(float x){ return 1.0f/(1.0f + __expf(-x)); }
__device__ __forceinline__ float tanh_f(float x){ return 1.0f - 2.0f/(1.0f + __expf(2.0f*x)); }

// coherent read-through 16B load, ISSUE ONLY (no wait): inline asm so the
// compiler can neither sink it nor shrink the in-flight window. sc0 sc1 =
// gfx950 coherent read (reads through to the coherence point).
__device__ __forceinline__ void cld16(h8& dst, const u16* p){
  asm volatile("global_load_dwordx4 %0, %1, off sc0 sc1" : "=v"(dst) : "v"(p));
}
// drain + scheduler fence (hipcc hoists register-only MFMA past inline-asm
// s_waitcnt; sched_barrier(0) is the documented fix). ONLY vmcnt(0) is used —
// counted vmcnt with 64 live staged regs crashed twice (rounds 11/13): the
// allocator moves asm "=v" outputs before the manual waitcnt.
__device__ __forceinline__ void vm_drain(){
  asm volatile("s_waitcnt vmcnt(0)" ::: "memory");
  __builtin_amdgcn_sched_barrier(0);
}
// per-16B staleness: each 4B granule is one producer u32 atomic store
// (both halves written together), so checking the low u16 of each dword
// suffices.
__device__ __forceinline__ bool stale16(h8 v){
  union { h8 h; unsigned d[4]; } u; u.h = v;
  bool b = false;
  #pragma unroll
  for (int k = 0; k < 4; ++k) b |= ((u.d[k] & 0xFFFFu) == SENT);
  return b;
}

// issue 32 forced-in-flight loads, drain, validate against sentinel; if ANY
// lane sees a stale granule, re-issue the WHOLE phase (bulk retry — the fix
// for round-6's serial per-unit retry chain). Wave-uniform branch via __any.
#define LOADV32(STARR, SRC, COLBASE) do {                                        \
  for(;;){                                                                       \
    _Pragma("unroll")                                                            \
    for (int i_ = 0; i_ < 8; ++i_){                                              \
      int col_ = (COLBASE) + i_*32 + quad*8;                                     \
      _Pragma("unroll")                                                          \
      for (int mt_ = 0; mt_ < 4; ++mt_)                                          \
        cld16(STARR[i_*4 + mt_], (SRC) + ((size_t)(mt_*16 + id) << 10) + col_);  \
    }                                                                            \
    vm_drain();                                                                  \
    bool bad_ = false;                                                           \
    _Pragma("unroll")                                                            \
    for (int i_ = 0; i_ < 32; ++i_) bad_ |= stale16(STARR[i_]);                  \
    if (!__any(bad_)) break;                                                     \
    __builtin_amdgcn_s_sleep(1);                                                 \
  }                                                                              \
} while(0)

// raw end-of-epoch barrier: LDS-order only, NO vmcnt drain. The h/reset
// stores stay in flight; they are drained for free at the NEXT epoch's
// exchange __syncthreads (~1 epoch later, latency fully elapsed).
__device__ __forceinline__ void end_barrier(){
  asm volatile("s_waitcnt lgkmcnt(0)\n\ts_barrier" ::: "memory");
}

// ---------------- prep kernels ----------------
__global__ void bias_comb_kernel(const float* __restrict__ a, const float* __restrict__ b,
                                 float* __restrict__ o, int n){
  int i = blockIdx.x*blockDim.x + threadIdx.x;
  if (i < n) o[i] = a[i] + b[i];
}

// h rings init: slot 0 = fp16 zeros (h[-1]); slots 1..15 = sentinel
__global__ void hinit_kernel(unsigned* __restrict__ h0, unsigned* __restrict__ h1){
  int i = blockIdx.x*blockDim.x + threadIdx.x;     // u32 index, 1<<19 per buf
  unsigned slot = ((unsigned)i) >> 15;             // 32768 u32 per slot
  unsigned v = (slot == 0) ? 0u : (SENT | (SENT << 16));
  h0[i] = v;
  h1[i] = v;
}

// x: [B][T][I] fp32 -> xb: [(t*B+b)][I] fp16
__global__ void xconv_kernel(const float* __restrict__ x, u16* __restrict__ xb){
  int m = blockIdx.x;            // t*BB + b
  int t = m >> 6, b = m & 63;
  const float4* src = (const float4*)(x + ((size_t)b*TT + t)*II);
  float4 v = src[threadIdx.x];   // 64 threads * 4 = 256 = II
  ushort4 o; o.x=f2h(v.x); o.y=f2h(v.y); o.z=f2h(v.z); o.w=f2h(v.w);
  ((ushort4*)(xb + (size_t)m*II))[threadIdx.x] = o;
}

// Concat-K weight swizzle into MFMA B-frag order (fp32 -> fp16).
// 8-j blocks: frag f in {0,1}; within frag, id in [0,16):
//   gate g = f*2 + (id>>3), j = jg8*8 + (id&7), n = g*HH + j
//   k = ks*32 + quad*8 + elem
// dst s8 = ((jg8*KS + ks)*2 + f)*64 + lane, 8 u16 each.
__global__ void wswz_kernel(const float* __restrict__ Wa, int Ka,
                            const float* __restrict__ Wb, int Kb,
                            u16* __restrict__ dst, int KS){
  int s8 = blockIdx.x*blockDim.x + threadIdx.x;
  int lane = s8 & 63;
  int f    = (s8 >> 6) & 1;
  int rest = s8 >> 7;
  int ks   = rest % KS;
  int jg8  = rest / KS;
  if (jg8 >= 128) return;
  int id = lane & 15, quad = lane >> 4;
  int g = f*2 + (id >> 3);
  int n = g*HH + jg8*8 + (id & 7);
  int k = ks*32 + quad*8;
  const float* src = (k < Ka) ? (Wa + (size_t)n*Ka + k) : (Wb + (size_t)n*Kb + (k - Ka));
  float4 v0 = ((const float4*)src)[0];
  float4 v1 = ((const float4*)src)[1];
  ushort4 o0; o0.x=f2h(v0.x); o0.y=f2h(v0.y); o0.z=f2h(v0.z); o0.w=f2h(v0.w);
  ushort4 o1; o1.x=f2h(v1.x); o1.y=f2h(v1.y); o1.z=f2h(v1.z); o1.w=f2h(v1.w);
  u16* d = dst + (size_t)s8*8;
  ((ushort4*)d)[0] = o0;
  ((ushort4*)d)[1] = o1;
}

// ---------------- fused 2-layer persistent LSTM, data-is-the-flag ----------------
// ROUND-12 COMPUTE STRUCTURE (verified: j=8 blocks, K-split waves, weights in
// regs, 32-deep forced staging, vmcnt(0)-only) + ROUND-6 SYNC PROTOCOL
// (verified-correct arithmetic) with the serial-retry flaw fixed by LOADV32's
// bulk retry.
//   producer (epoch t): store h[t] -> slot (t+1)&15 (relaxed agent u32);
//     pre-reset slot (t+9)&15 to sentinel; raw lgkm-only end barrier (NO
//     store drain); L1 publishes stamp1=t+1 after the barrier (progress
//     counter for L0's anti-overwrite credit only).
//   consumer: LOADV32 (issue 32 / drain / validate / bulk-retry). No stamp
//     waits anywhere on the critical path.
// Ring safety (16 slots, reset lead +9): same-layer skew <= 1 epoch (mutual
// data dependence each epoch); reset of h[t-8]'s slot has readers at >= t-1;
// L0's y0 reset guarded by lazy credit (L1 >= t-7); reset->write same thread
// same address -> per-location atomic-store ordering, no fence needed.
__launch_bounds__(256, 1)
__global__ void lstm_fused_kernel(const u16* __restrict__ xb,
                                  const u16* __restrict__ Wsw0,
                                  const u16* __restrict__ Wsw1,
                                  const float* __restrict__ bias0,
                                  const float* __restrict__ bias1,
                                  u16* __restrict__ h0buf,   // 16 slots [64][1024] fp16
                                  u16* __restrict__ h1buf,   // 16 slots
                                  float* __restrict__ hfin,  // [2][64][1024] fp32
                                  int* __restrict__ stamp1){ // 128 slots, stride 32 ints
  __shared__ float Gs[4][32][68];    // [wave][gate-row 2f x 16id][batch 64+pad]
  const int blk = blockIdx.x;
  const int layer = blk >> 7;
  const int jg = blk & 127;
  const int tid = threadIdx.x, wave = tid >> 6, lane = tid & 63;
  const int id = lane & 15, quad = lane >> 4;
  const int KS = layer ? 64 : 40;
  const u16* Wblk = (layer ? Wsw1 : Wsw0) + (size_t)jg * KS * 1024;
  const int cb = tid >> 2, jq = tid & 3;  // cell phase: batch cb, j-pair jq
  const int j0 = jg * 8;
  const float* Bp = layer ? bias1 : bias0;
  float bs[4][2];
  #pragma unroll
  for (int g = 0; g < 4; ++g)
    #pragma unroll
    for (int jj = 0; jj < 2; ++jj)
      bs[g][jj] = Bp[g*HH + j0 + jq*2 + jj];
  float c2[2] = {0.f, 0.f};

  if (layer == 0){
    // ---- weights: wave w owns x-ksteps {2w,2w+1} + h-ksteps {8+8w..8+8w+7} ----
    h8 w0[10], w1[10];
    #pragma unroll
    for (int i = 0; i < 10; ++i){
      int ks = (i < 2) ? (2*wave + i) : (8 + 8*wave + (i - 2));
      const u16* wl = Wblk + (size_t)ks*1024 + lane*8;
      w0[i] = *(const h8*)(wl);
      w1[i] = *(const h8*)(wl + 512);
    }
    int credit = 0;
    for (int t = 0; t < TT; ++t){
      const u16* hA = h0buf + ((size_t)(t & 15) << 16);        // h0[t-1]
      u16* hout     = h0buf + ((size_t)((t + 1) & 15) << 16);  // h0[t]
      u16* hrst     = h0buf + ((size_t)((t + 9) & 15) << 16);  // pre-reset target
      f32x4 a0[4] = {}, a1[4] = {};
      // ---- x-part: h-independent (plain cached loads) ----
      #pragma unroll
      for (int i = 0; i < 2; ++i){
        int xcol = (2*wave + i)*32 + quad*8;
        #pragma unroll
        for (int mt = 0; mt < 4; ++mt){
          h8 A = *(const h8*)(xb + (((size_t)t*64 + mt*16 + id) << 8) + xcol);
          a0[mt] = __builtin_amdgcn_mfma_f32_16x16x32_f16(A, w0[i], a0[mt], 0,0,0);
          a1[mt] = __builtin_amdgcn_mfma_f32_16x16x32_f16(A, w1[i], a1[mt], 0,0,0);
        }
      }
      // ---- lazy anti-overwrite credit (wave0): reset target slot (t+9)&15
      //      holds y0[t-8]; L1 must be >= t-7. Stores/resets happen after the
      //      exchange barrier, so wave0's check transitively guards all waves.
      if (wave == 0){
        while (credit < t - 7){
          int sa = __hip_atomic_load(stamp1 + lane*32,      __ATOMIC_RELAXED, __HIP_MEMORY_SCOPE_AGENT);
          int sb = __hip_atomic_load(stamp1 + (64+lane)*32, __ATOMIC_RELAXED, __HIP_MEMORY_SCOPE_AGENT);
          int s = sa < sb ? sa : sb;
          #pragma unroll
          for (int off = 32; off; off >>= 1){
            int s2 = __shfl_xor(s, off);
            s = s < s2 ? s : s2;
          }
          credit = s;
          if (credit < t - 7) __builtin_amdgcn_s_sleep(8);
        }
      }
      // ---- h-part: validated bulk load (cols [wave*256,+256)), then 64 MFMA ----
      {
        h8 st[32];
        LOADV32(st, hA, wave*256);
        #pragma unroll
        for (int i = 0; i < 8; ++i)
          #pragma unroll
          for (int mt = 0; mt < 4; ++mt){
            a0[mt] = __builtin_amdgcn_mfma_f32_16x16x32_f16(st[i*4+mt], w0[2+i], a0[mt], 0,0,0);
            a1[mt] = __builtin_amdgcn_mfma_f32_16x16x32_f16(st[i*4+mt], w1[2+i], a1[mt], 0,0,0);
          }
      }
      // ---- exchange: D lane(id,quad) reg r -> batch mt*16+quad*4+r, row f*16+id ----
      #pragma unroll
      for (int mt = 0; mt < 4; ++mt){
        *(f32x4*)&Gs[wave][id][mt*16 + quad*4]      = a0[mt];
        *(f32x4*)&Gs[wave][16 + id][mt*16 + quad*4] = a1[mt];
      }
      __syncthreads();   // exchange barrier (also drains PREVIOUS epoch's stores, free)
      // ---- cell phase: 2 cells (batch cb, j = j0 + jq*2 + jj) ----
      ushort2 hb; float2 hf;
      #pragma unroll
      for (int jj = 0; jj < 2; ++jj){
        int jl = jq*2 + jj;
        float p[4];
        #pragma unroll
        for (int g = 0; g < 4; ++g){
          int e = (g >> 1)*16 + (g & 1)*8 + jl;
          p[g] = Gs[0][e][cb] + Gs[1][e][cb] + Gs[2][e][cb] + Gs[3][e][cb] + bs[g][jj];
        }
        float iv = sigm(p[0]), fv = sigm(p[1]), gv = tanh_f(p[2]), ov = sigm(p[3]);
        float c = fv*c2[jj] + iv*gv;
        c2[jj] = c;
        float h = ov * tanh_f(c);
        (&hf.x)[jj] = h;
        ((u16*)&hb)[jj] = f2h(h);
      }
      union { ushort2 s; unsigned int v; } pk; pk.s = hb;
      __hip_atomic_store((unsigned int*)&hout[(size_t)cb*HH + j0 + jq*2],
                         pk.v, __ATOMIC_RELAXED, __HIP_MEMORY_SCOPE_AGENT);
      __hip_atomic_store((unsigned int*)&hrst[(size_t)cb*HH + j0 + jq*2],
                         SENT | (SENT << 16), __ATOMIC_RELAXED, __HIP_MEMORY_SCOPE_AGENT);
      if (t == TT - 1)
        *(float2*)&hfin[(size_t)cb*HH + j0 + jq*2] = hf;
      end_barrier();     // raw lgkm-only barrier: stores stay in flight
    }
  } else {
    // ---- preload weight fragment: 16 steps x 2 frags = 128 regs ----
    h8 w0[16], w1[16];
    const int wb = wave * 16;
    #pragma unroll
    for (int l = 0; l < 16; ++l){
      const u16* wl = Wblk + (size_t)(wb + l)*1024 + lane*8;
      w0[l] = *(const h8*)(wl);
      w1[l] = *(const h8*)(wl + 512);
    }
    // wave w covers k [w*512, (w+1)*512): waves 0-1 read y0, waves 2-3 read h1
    const int koff = (wave & 1) * 512;
    for (int t = 0; t < TT; ++t){
      const u16* y0  = h0buf + ((size_t)((t + 1) & 15) << 16); // y0[t] = h0[t]
      const u16* hA1 = h1buf + ((size_t)(t & 15) << 16);       // h1[t-1]
      u16* hout      = h1buf + ((size_t)((t + 1) & 15) << 16); // h1[t]
      u16* hrst      = h1buf + ((size_t)((t + 9) & 15) << 16);
      const u16* hsrc = (wave < 2) ? y0 : hA1;
      f32x4 a0[4] = {}, a1[4] = {};
      // ---- phase A: validated bulk load (ksteps 0-7), 64 MFMA ----
      {
        h8 st[32];
        LOADV32(st, hsrc, koff);
        #pragma unroll
        for (int l = 0; l < 8; ++l)
          #pragma unroll
          for (int mt = 0; mt < 4; ++mt){
            a0[mt] = __builtin_amdgcn_mfma_f32_16x16x32_f16(st[l*4+mt], w0[l], a0[mt], 0,0,0);
            a1[mt] = __builtin_amdgcn_mfma_f32_16x16x32_f16(st[l*4+mt], w1[l], a1[mt], 0,0,0);
          }
      }
      // ---- phase B: validated bulk load (ksteps 8-15), 64 MFMA ----
      {
        h8 st[32];
        LOADV32(st, hsrc, koff + 256);
        #pragma unroll
        for (int l = 0; l < 8; ++l)
          #pragma unroll
          for (int mt = 0; mt < 4; ++mt){
            a0[mt] = __builtin_amdgcn_mfma_f32_16x16x32_f16(st[l*4+mt], w0[8+l], a0[mt], 0,0,0);
            a1[mt] = __builtin_amdgcn_mfma_f32_16x16x32_f16(st[l*4+mt], w1[8+l], a1[mt], 0,0,0);
          }
      }
      #pragma unroll
      for (int mt = 0; mt < 4; ++mt){
        *(f32x4*)&Gs[wave][id][mt*16 + quad*4]      = a0[mt];
        *(f32x4*)&Gs[wave][16 + id][mt*16 + quad*4] = a1[mt];
      }
      __syncthreads();   // exchange barrier (drains previous epoch's stores, free)
      ushort2 hb; float2 hf;
      #pragma unroll
      for (int jj = 0; jj < 2; ++jj){
        int jl = jq*2 + jj;
        float p[4];
        #pragma unroll
        for (int g = 0; g < 4; ++g){
          int e = (g >> 1)*16 + (g & 1)*8 + jl;
          p[g] = Gs[0][e][cb] + Gs[1][e][cb] + Gs[2][e][cb] + Gs[3][e][cb] + bs[g][jj];
        }
        float iv = sigm(p[0]), fv = sigm(p[1]), gv = tanh_f(p[2]), ov = sigm(p[3]);
        float c = fv*c2[jj] + iv*gv;
        c2[jj] = c;
        float h = ov * tanh_f(c);
        (&hf.x)[jj] = h;
        ((u16*)&hb)[jj] = f2h(h);
      }
      union { ushort2 s; unsigned int v; } pk; pk.s = hb;
      __hip_atomic_store((unsigned int*)&hout[(size_t)cb*HH + j0 + jq*2],
                         pk.v, __ATOMIC_RELAXED, __HIP_MEMORY_SCOPE_AGENT);
      __hip_atomic_store((unsigned int*)&hrst[(size_t)cb*HH + j0 + jq*2],
                         SENT | (SENT << 16), __ATOMIC_RELAXED, __HIP_MEMORY_SCOPE_AGENT);
      if (t == TT - 1)
        *(float2*)&hfin[(size_t)(BB*HH) + (size_t)cb*HH + j0 + jq*2] = hf;
      end_barrier();     // raw lgkm-only barrier: stores stay in flight
      // progress stamp for L0's credit (off critical path): y0[t] reads were
      // consumed before the exchange barrier, so t+1 attests reads-done.
      if (tid == 0)
        __hip_atomic_store(stamp1 + jg*32, t + 1, __ATOMIC_RELAXED, __HIP_MEMORY_SCOPE_AGENT);
    }
  }
}

// ---------------- FC head ----------------
__global__ void fc_kernel(const float* __restrict__ hfin, const float* __restrict__ fcw,
                          const float* __restrict__ fcb, float* __restrict__ out){
  int row = blockIdx.x;          // 0..127  (0..63 layer0 hT, 64..127 layer1 hT)
  int lane = threadIdx.x;        // 64
  const float* h = hfin + (size_t)row*HH;
  float a0 = 0.f, a1 = 0.f;
  for (int j = lane; j < HH; j += 64){
    float v = h[j]; v = v > 0.f ? v : 0.f;
    a0 += v * fcw[j];
    a1 += v * fcw[HH + j];
  }
  for (int off = 32; off; off >>= 1){ a0 += __shfl_down(a0, off); a1 += __shfl_down(a1, off); }
  if (lane == 0){
    out[row*2 + 0] = 1.f/(1.f + __expf(-(a0 + fcb[0])));
    out[row*2 + 1] = 1.f/(1.f + __expf(-(a1 + fcb[1])));
  }
}

// ---------------- launch ----------------
extern "C" void kernel_launch(void* const* d_in, const int* in_sizes, int n_in,
                              void* d_out, int out_size, void* d_ws, size_t ws_size,
                              hipStream_t stream){
  (void)in_sizes; (void)n_in; (void)out_size; (void)ws_size;
  const float* x    = (const float*)d_in[0];
  const float* Wih0 = (const float*)d_in[1];
  const float* Whh0 = (const float*)d_in[2];
  const float* bih0 = (const float*)d_in[3];
  const float* bhh0 = (const float*)d_in[4];
  const float* Wih1 = (const float*)d_in[5];
  const float* Whh1 = (const float*)d_in[6];
  const float* bih1 = (const float*)d_in[7];
  const float* bhh1 = (const float*)d_in[8];
  const float* fcw  = (const float*)d_in[9];
  const float* fcb  = (const float*)d_in[10];

  char* w = (char*)d_ws;
  size_t off = 0;
  auto take = [&](size_t bytes)->char*{
    char* p = w + off; off += (bytes + 255) & ~(size_t)255; return p;
  };
  u16*   xb    = (u16*)  take((size_t)TT*BB*II*2);       // 16 MB
  u16*   wsw0  = (u16*)  take((size_t)G4*1280*2);        // 10 MB  (K=256+1024)
  u16*   wsw1  = (u16*)  take((size_t)G4*2048*2);        // 16 MB  (K=1024+1024)
  float* bias0 = (float*)take(G4*4);
  float* bias1 = (float*)take(G4*4);
  u16*   h0buf = (u16*)  take(16*(size_t)BB*HH*2);       // 2 MB ring (16 slots)
  u16*   h1buf = (u16*)  take(16*(size_t)BB*HH*2);
  float* hfin  = (float*)take(2*(size_t)BB*HH*4);        // 512 KB
  int*   stamp1= (int*)  take(128*128);                  // 128 slots x 128B

  hipMemsetAsync(stamp1, 0, 128*128, stream);

  bias_comb_kernel<<<16, 256, 0, stream>>>(bih0, bhh0, bias0, G4);
  bias_comb_kernel<<<16, 256, 0, stream>>>(bih1, bhh1, bias1, G4);
  hinit_kernel<<<2048, 256, 0, stream>>>((unsigned*)h0buf, (unsigned*)h1buf);
  xconv_kernel<<<TT*BB, 64, 0, stream>>>(x, xb);
  // L0: 128*40*2*64/256 = 2560 blocks; L1: 128*64*2*64/256 = 4096 blocks
  wswz_kernel<<<2560, 256, 0, stream>>>(Wih0, II, Whh0, HH, wsw0, 40);
  wswz_kernel<<<4096, 256, 0, stream>>>(Wih1, HH, Whh1, HH, wsw1, 64);

  lstm_fused_kernel<<<256, 256, 0, stream>>>(xb, wsw0, wsw1, bias0, bias1,
                                             h0buf, h1buf, hfin, stamp1);
  fc_kernel<<<2*BB, 64, 0, stream>>>(hfin, fcw, fcb, (float*)d_out);
}